// Round 8
// baseline (1681.271 us; speedup 1.0000x reference)
//
#include <hip/hip_runtime.h>

// z: [32, 256, 32, 32] f32 -> zf: [N=32768, D=256];  emb_w: [K=1024, D=256] f32
// out: z_q (8388608 f32, BCHW) | loss (1 f32) | codes (131072 f32, BHW x DEPTH)
// Bitwise-np distance pipeline (passing since R4):
//   t1 = np pairwise sum (128-block, 8-acc, fixed tree), dot = sequential-k FMA,
//   d = fl(fl(t1+t2) - 2*dot), argmin first-index tie-break, res -= emb[code].
// R8: VGPR budget is hard-capped ~64 on this compile path (R4/R6/R7: VGPR=64
//     regardless of launch_bounds/waves_per_eu/SSA form; 64-float acc state
//     spilled every time, 0.35-1.1 GB scratch HBM traffic). Fix: 16 rows/block
//     x 2048 blocks -> 32 acc floats/thread (~55 VGPR total) -> nothing to spill.
//     All per-element FP chains identical to R4 -> codes bitwise-unchanged.

#define GLD_G const __attribute__((address_space(1))) void*
#define GLD_L __attribute__((address_space(3))) void*

// ---------------- prep: transpose emb -> embT [256][1024] (pure copy) ----------------
__global__ __launch_bounds__(256) void prep_transpose(const float* __restrict__ emb,
                                                      float* __restrict__ embT) {
  __shared__ float tile[64][65];
  int tb = blockIdx.x;
  int c0 = (tb & 15) << 6;
  int d0 = (tb >> 4) << 6;
  int tx = threadIdx.x & 63;
  int ty = threadIdx.x >> 6;
#pragma unroll
  for (int i = 0; i < 16; ++i) {
    int c = (i << 2) + ty;
    tile[c][tx] = emb[(c0 + c) * 256 + d0 + tx];
  }
  __syncthreads();
#pragma unroll
  for (int i = 0; i < 16; ++i) {
    int d = (i << 2) + ty;
    embT[(d0 + d) * 1024 + c0 + tx] = tile[tx][d];
  }
}

// ---------------- prep: t2[c] = ||e_c||^2 via numpy pairwise order; zero loss ----------------
__global__ __launch_bounds__(256) void prep_t2(const float* __restrict__ emb,
                                               float* __restrict__ t2,
                                               float* __restrict__ out) {
#pragma clang fp contract(off)
  __shared__ float partials[16][16];
  int ci = threadIdx.x >> 4, part = threadIdx.x & 15;
  int bb = part >> 3, jj = part & 7;
  int c = (blockIdx.x << 4) + ci;
  const float* e = emb + c * 256 + bb * 128 + jj;
  float x = e[0];
  float acc = x * x;
  for (int i = 1; i < 16; ++i) { float y = e[i * 8]; acc = acc + y * y; }
  partials[ci][part] = acc;
  __syncthreads();
  if (part == 0) {
    const float* p = partials[ci];
    float B0 = ((p[0] + p[1]) + (p[2] + p[3])) + ((p[4] + p[5]) + (p[6] + p[7]));
    float B1 = ((p[8] + p[9]) + (p[10] + p[11])) + ((p[12] + p[13]) + (p[14] + p[15]));
    t2[c] = B0 + B1;
    if (c == 0) out[8388608] = 0.0f;
  }
}

// FMA micro-step: one float4 of A rows against bv (cols 0,1). k-ascending per chain.
#define STEP(CA, CB)                                                      \
  CA.x = __builtin_fmaf(a4.x, bv.x, CA.x); CB.x = __builtin_fmaf(a4.x, bv.y, CB.x); \
  CA.y = __builtin_fmaf(a4.y, bv.x, CA.y); CB.y = __builtin_fmaf(a4.y, bv.y, CB.y); \
  CA.z = __builtin_fmaf(a4.z, bv.x, CA.z); CB.z = __builtin_fmaf(a4.z, bv.y, CB.z); \
  CA.w = __builtin_fmaf(a4.w, bv.x, CA.w); CB.w = __builtin_fmaf(a4.w, bv.y, CB.w);

// Per-row distance + 64-lane argmin butterfly + per-wave stash.
#define ARGMIN_ROW(r, a0, a1) {                                           \
    float t1r = t1s[r];                                                   \
    float d0 = (t1r + tc0) - 2.0f * (a0);                                 \
    float d1 = (t1r + tc1) - 2.0f * (a1);                                 \
    float v = d0; int ci = colbase;                                       \
    if (d1 < v) { v = d1; ci = colbase + 1; }                             \
    _Pragma("unroll")                                                     \
    for (int m = 1; m < 64; m <<= 1) {                                    \
      float ov = __shfl_xor(v, m, 64);                                    \
      int oi = __shfl_xor(ci, m, 64);                                     \
      bool better = (ov < v) || (ov == v && oi < ci);                     \
      v = better ? ov : v;                                                \
      ci = better ? oi : ci;                                              \
    }                                                                     \
    if (l == 0) { redv[((r) << 3) + w] = v; redi[((r) << 3) + w] = ci; } }

// ---------------- main fused kernel: 4 faithful f32 GEMM+argmin rounds ----------------
// Block: 512 threads (8 waves), 16 rows x 1024 codes. Wave w owns cols [128w,128w+128).
// Per thread: 16 rows x 2 cols = 32 acc floats -> fits the observed 64-VGPR cap.
__global__ __launch_bounds__(512)
void rq_main(const float* __restrict__ z,
             const float* __restrict__ emb,
             const float* __restrict__ embT,
             const float* __restrict__ t2g,
             float* __restrict__ out) {
  __shared__ float At[256 * 20];     // res transposed [k][r], 16 rows pad to 20
  __shared__ float Bb[8 * 1024];     // embT K-chunk
  __shared__ float t2s[1024];
  __shared__ float t1part[16][16];   // pairwise partials per row
  __shared__ float t1s[16];
  __shared__ float redv[128];
  __shared__ int redi[128];
  __shared__ int codes_l[64];        // [16 rows][4 depths]
  __shared__ float lossAcc;

  const int tid = threadIdx.x;
  const int w = tid >> 6, l = tid & 63;
  const int n0 = blockIdx.x << 4;
  const int b = n0 >> 10, hw0 = n0 & 1023;
  const float* zbase = z + b * 262144 + hw0;

  // stage zf (transposed) into At: 256k x 16r = 1024 float4, 2 per thread
#pragma unroll
  for (int it = 0; it < 2; ++it) {
    int idx = it * 512 + tid;
    int k = idx >> 2, r4 = (idx & 3) << 2;
    *(float4*)(&At[k * 20 + r4]) = *(const float4*)(zbase + k * 1024 + r4);
  }
  // stage t2
  {
    int i = tid << 1;
    float2 v = *(const float2*)(t2g + i);
    t2s[i] = v.x; t2s[i + 1] = v.y;
  }
  if (tid == 0) lossAcc = 0.0f;
  __syncthreads();

  const int colbase = (w << 7) + (l << 1);
  const int rr1 = tid & 15, part1 = tid >> 4;              // t1: 16 rows x 16 parts (tid<256)
  const int kb0_ = ((part1 & 15) >> 3) * 128 + (part1 & 7);
  const int rr2 = tid & 15, part2 = tid >> 4;              // res-sub: 16 rows x 32 parts x 8k

  for (int t = 0; t < 4; ++t) {
    // ---- t1 = numpy pairwise sum of res^2 per row (bitwise) ----
    if (tid < 256) {
#pragma clang fp contract(off)
      float x = At[kb0_ * 20 + rr1];
      float acc = x * x;
      for (int i = 1; i < 16; ++i) {
        float y = At[(kb0_ + i * 8) * 20 + rr1];
        acc = acc + y * y;
      }
      t1part[rr1][part1] = acc;
    }
    __syncthreads();
    if (tid < 16) {
#pragma clang fp contract(off)
      const float* p = t1part[tid];
      float B0 = ((p[0] + p[1]) + (p[2] + p[3])) + ((p[4] + p[5]) + (p[6] + p[7]));
      float B1 = ((p[8] + p[9]) + (p[10] + p[11])) + ((p[12] + p[13]) + (p[14] + p[15]));
      t1s[tid] = B0 + B1;
    }
    __syncthreads();
    if (t > 0 && tid == 0) {
      float s = 0.0f;
      for (int r = 0; r < 16; ++r) s += t1s[r];
      lossAcc += s;  // sum res_t^2, t = 1..3 here; final term added after loop
    }

    // ---- GEMM: dot[r][j] = sequential-k FMA chain; 8 named float4 accumulators ----
    float4 c00 = {0.f, 0.f, 0.f, 0.f}, c01 = c00, c02 = c00, c03 = c00;
    float4 c10 = c00, c11 = c00, c12 = c00, c13 = c00;
    for (int kc = 0; kc < 32; ++kc) {
      const float* src = embT + (kc << 13);
#pragma unroll
      for (int it = 0; it < 4; ++it) {
        int base = it * 2048 + (w << 8);
        __builtin_amdgcn_global_load_lds((GLD_G)(src + base + (l << 2)),
                                         (GLD_L)(Bb + base), 16, 0, 0);
      }
      __syncthreads();
#pragma unroll
      for (int k = 0; k < 8; ++k) {
        const float* arow = &At[(kc * 8 + k) * 20];
        float2 bv = *(const float2*)(&Bb[(k << 10) + colbase]);
        float4 a4;
        a4 = *(const float4*)(arow + 0);  STEP(c00, c10)
        a4 = *(const float4*)(arow + 4);  STEP(c01, c11)
        a4 = *(const float4*)(arow + 8);  STEP(c02, c12)
        a4 = *(const float4*)(arow + 12); STEP(c03, c13)
      }
      __syncthreads();
    }

    // ---- d = fl(fl(t1+t2) - 2*dot); argmin with first-index tie-break ----
    {
      const float tc0 = t2s[colbase];
      const float tc1 = t2s[colbase + 1];
      ARGMIN_ROW(0,  c00.x, c10.x) ARGMIN_ROW(1,  c00.y, c10.y)
      ARGMIN_ROW(2,  c00.z, c10.z) ARGMIN_ROW(3,  c00.w, c10.w)
      ARGMIN_ROW(4,  c01.x, c11.x) ARGMIN_ROW(5,  c01.y, c11.y)
      ARGMIN_ROW(6,  c01.z, c11.z) ARGMIN_ROW(7,  c01.w, c11.w)
      ARGMIN_ROW(8,  c02.x, c12.x) ARGMIN_ROW(9,  c02.y, c12.y)
      ARGMIN_ROW(10, c02.z, c12.z) ARGMIN_ROW(11, c02.w, c12.w)
      ARGMIN_ROW(12, c03.x, c13.x) ARGMIN_ROW(13, c03.y, c13.y)
      ARGMIN_ROW(14, c03.z, c13.z) ARGMIN_ROW(15, c03.w, c13.w)
    }
    __syncthreads();
    if (tid < 16) {
      int r = tid;
      float v = redv[r << 3];
      int ci = redi[r << 3];
#pragma unroll
      for (int w2 = 1; w2 < 8; ++w2) {
        float ov = redv[(r << 3) + w2];
        int oi = redi[(r << 3) + w2];
        bool better = (ov < v) || (ov == v && oi < ci);
        v = better ? ov : v;
        ci = better ? oi : ci;
      }
      codes_l[(r << 2) + t] = ci;
    }
    __syncthreads();

    // ---- res -= emb[code]  (elementwise f32, bitwise): 32 threads/row x 8 k ----
    {
      int c = codes_l[(rr2 << 2) + t];
      int kstart = part2 << 3;
      const float* er = emb + (c << 8) + kstart;
      float4 e0 = *(const float4*)(er);
      float4 e1 = *(const float4*)(er + 4);
      At[(kstart + 0) * 20 + rr2] -= e0.x;  At[(kstart + 1) * 20 + rr2] -= e0.y;
      At[(kstart + 2) * 20 + rr2] -= e0.z;  At[(kstart + 3) * 20 + rr2] -= e0.w;
      At[(kstart + 4) * 20 + rr2] -= e1.x;  At[(kstart + 5) * 20 + rr2] -= e1.y;
      At[(kstart + 6) * 20 + rr2] -= e1.z;  At[(kstart + 7) * 20 + rr2] -= e1.w;
    }
    __syncthreads();
  }  // depth loop

  // ---- final loss term: sumsq(res_4) ----
  if (tid < 256) {
#pragma clang fp contract(off)
    float x = At[kb0_ * 20 + rr1];
    float acc = x * x;
    for (int i = 1; i < 16; ++i) {
      float y = At[(kb0_ + i * 8) * 20 + rr1];
      acc = acc + y * y;
    }
    t1part[rr1][part1] = acc;
  }
  __syncthreads();
  if (tid < 16) {
#pragma clang fp contract(off)
    const float* p = t1part[tid];
    float B0 = ((p[0] + p[1]) + (p[2] + p[3])) + ((p[4] + p[5]) + (p[6] + p[7]));
    float B1 = ((p[8] + p[9]) + (p[10] + p[11])) + ((p[12] + p[13]) + (p[14] + p[15]));
    t1s[tid] = B0 + B1;
  }
  __syncthreads();
  if (tid == 0) {
    float s = 0.0f;
    for (int r = 0; r < 16; ++r) s += t1s[r];
    float total = lossAcc + s;  // sum_{t=1..4} sum res_t^2
    atomicAdd(out + 8388608, total * (11.0f / 8388608.0f));
  }
  __syncthreads();

  // ---- z_q = agg chain. wave w -> rows 2w,2w+1; lane l -> dims 4l..4l+3 ----
  const int r0 = w << 1;
  float4 g0 = {0.f, 0.f, 0.f, 0.f}, g1 = g0;
#pragma unroll
  for (int t = 0; t < 4; ++t) {
#define AGG_ROW(G, rr) {                                                  \
      int c = codes_l[((r0 + (rr)) << 2) + t];                            \
      float4 e4 = *(const float4*)(emb + (c << 8) + (l << 2));            \
      G.x += e4.x; G.y += e4.y; G.z += e4.z; G.w += e4.w; }
    AGG_ROW(g0, 0) AGG_ROW(g1, 1)
#undef AGG_ROW
  }
#define STORE_AGG(G, rr)                                                  \
  At[((l << 2) + 0) * 20 + r0 + (rr)] = G.x;                              \
  At[((l << 2) + 1) * 20 + r0 + (rr)] = G.y;                              \
  At[((l << 2) + 2) * 20 + r0 + (rr)] = G.z;                              \
  At[((l << 2) + 3) * 20 + r0 + (rr)] = G.w;
  STORE_AGG(g0, 0) STORE_AGG(g1, 1)
#undef STORE_AGG
  __syncthreads();
  float* zqbase = out + b * 262144 + hw0;
#pragma unroll
  for (int it = 0; it < 8; ++it) {
    int d = (it << 5) + (tid >> 4);
    int r = tid & 15;
    zqbase[d * 1024 + r] = At[d * 20 + r];
  }
  // codes as f32
  if (tid < 64) {
    int n = tid >> 2, tt = tid & 3;
    out[8388609 + ((n0 + n) << 2) + tt] = (float)codes_l[(n << 2) + tt];
  }
}

extern "C" void kernel_launch(void* const* d_in, const int* in_sizes, int n_in,
                              void* d_out, int out_size, void* d_ws, size_t ws_size,
                              hipStream_t stream) {
  const float* z = (const float*)d_in[0];
  const float* emb = (const float*)d_in[1];
  float* out = (float*)d_out;
  float* ws = (float*)d_ws;
  float* embT = ws;            // 262144 f32
  float* t2 = ws + 262144;     // 1024 f32

  hipLaunchKernelGGL(prep_transpose, dim3(64), dim3(256), 0, stream, emb, embT);
  hipLaunchKernelGGL(prep_t2, dim3(64), dim3(256), 0, stream, emb, t2, out);
  hipLaunchKernelGGL(rq_main, dim3(2048), dim3(512), 0, stream, z, emb, embT, t2, out);
}

// Round 10
// 1118.020 us; speedup vs baseline: 1.5038x; 1.5038x over previous
//
#include <hip/hip_runtime.h>

// z: [32, 256, 32, 32] f32 -> zf: [N=32768, D=256];  emb_w: [K=1024, D=256] f32
// out: z_q (8388608 f32, BCHW) | loss (1 f32) | codes (131072 f32, BHW x DEPTH)
// Bitwise-np distance pipeline (passing since R4, absmax 12.0):
//   t1 = np pairwise sum (128-block, 8-acc, fixed tree), dot = sequential-k FMA,
//   d = fl(fl(t1+t2) - 2*dot), argmin first-index tie-break, res -= emb[code].
// R9: (a) 4 cols/thread (16 named float4 accs; LDS instrs per 64 FMAs: 9 -> 5),
//     (b) double-buffered B staging, STAGE(next) before compute(cur), one
//     sync/step (T3-minimum pipeline). 32 rows x 1024 cols/block, 1024 blocks.
//     All per-(row,col) FP chains identical to R4 -> codes bitwise-unchanged.
//     R8 evidence: spills fixed (VGPR 84, WRITE 33MB) but serial stage+drain
//     and LDS-pipe pressure dominate -> this round attacks those.

#define GLD_G const __attribute__((address_space(1))) void*
#define GLD_L __attribute__((address_space(3))) void*

// ---------------- prep: transpose emb -> embT [256][1024] (pure copy) ----------------
__global__ __launch_bounds__(256) void prep_transpose(const float* __restrict__ emb,
                                                      float* __restrict__ embT) {
  __shared__ float tile[64][65];
  int tb = blockIdx.x;
  int c0 = (tb & 15) << 6;
  int d0 = (tb >> 4) << 6;
  int tx = threadIdx.x & 63;
  int ty = threadIdx.x >> 6;
#pragma unroll
  for (int i = 0; i < 16; ++i) {
    int c = (i << 2) + ty;
    tile[c][tx] = emb[(c0 + c) * 256 + d0 + tx];
  }
  __syncthreads();
#pragma unroll
  for (int i = 0; i < 16; ++i) {
    int d = (i << 2) + ty;
    embT[(d0 + d) * 1024 + c0 + tx] = tile[tx][d];
  }
}

// ---------------- prep: t2[c] = ||e_c||^2 via numpy pairwise order; zero loss ----------------
__global__ __launch_bounds__(256) void prep_t2(const float* __restrict__ emb,
                                               float* __restrict__ t2,
                                               float* __restrict__ out) {
#pragma clang fp contract(off)
  __shared__ float partials[16][16];
  int ci = threadIdx.x >> 4, part = threadIdx.x & 15;
  int bb = part >> 3, jj = part & 7;
  int c = (blockIdx.x << 4) + ci;
  const float* e = emb + c * 256 + bb * 128 + jj;
  float x = e[0];
  float acc = x * x;
  for (int i = 1; i < 16; ++i) { float y = e[i * 8]; acc = acc + y * y; }
  partials[ci][part] = acc;
  __syncthreads();
  if (part == 0) {
    const float* p = partials[ci];
    float B0 = ((p[0] + p[1]) + (p[2] + p[3])) + ((p[4] + p[5]) + (p[6] + p[7]));
    float B1 = ((p[8] + p[9]) + (p[10] + p[11])) + ((p[12] + p[13]) + (p[14] + p[15]));
    t2[c] = B0 + B1;
    if (c == 0) out[8388608] = 0.0f;
  }
}

// componentwise FMA: C += A * s, per-element chains k-ascending (bitwise = R4)
#define FM(C, A, S)                                                       \
  C.x = __builtin_fmaf(A.x, (S), C.x); C.y = __builtin_fmaf(A.y, (S), C.y); \
  C.z = __builtin_fmaf(A.z, (S), C.z); C.w = __builtin_fmaf(A.w, (S), C.w);

// Per-row: 4 in-thread cols (ascending, strict <), 64-lane butterfly, stash.
#define ARGMIN_ROW4(r, A0, A1, A2, A3) {                                  \
    float t1r = t1s[r];                                                   \
    float d0 = (t1r + tc.x) - 2.0f * (A0);                                \
    float d1 = (t1r + tc.y) - 2.0f * (A1);                                \
    float d2 = (t1r + tc.z) - 2.0f * (A2);                                \
    float d3 = (t1r + tc.w) - 2.0f * (A3);                                \
    float v = d0; int ci = colbase;                                       \
    if (d1 < v) { v = d1; ci = colbase + 1; }                             \
    if (d2 < v) { v = d2; ci = colbase + 2; }                             \
    if (d3 < v) { v = d3; ci = colbase + 3; }                             \
    _Pragma("unroll")                                                     \
    for (int m = 1; m < 64; m <<= 1) {                                    \
      float ov = __shfl_xor(v, m, 64);                                    \
      int oi = __shfl_xor(ci, m, 64);                                     \
      bool better = (ov < v) || (ov == v && oi < ci);                     \
      v = better ? ov : v;                                                \
      ci = better ? oi : ci;                                              \
    }                                                                     \
    if (l == 0) { redv[((r) << 2) + wg] = v; redi[((r) << 2) + wg] = ci; } }

// stage one 4k x 1024 chunk (16KB) into Bb[BUF]; 2 loads per wave, linear dest
#define STAGE(BUF, KC) {                                                  \
    int off0 = (w << 9) + (l << 2);                                       \
    __builtin_amdgcn_global_load_lds((GLD_G)(embT + ((KC) << 12) + off0), \
                                     (GLD_L)(&Bb[BUF][0] + off0), 16, 0, 0); \
    __builtin_amdgcn_global_load_lds((GLD_G)(embT + ((KC) << 12) + off0 + 256), \
                                     (GLD_L)(&Bb[BUF][0] + off0 + 256), 16, 0, 0); }

// ---------------- main fused kernel: 4 faithful f32 GEMM+argmin rounds ----------------
// 1024 blocks x 512 threads. Block: 32 rows x 1024 cols. Thread: 16 rows x 4 cols.
// Row-group g = tid>>8 (rows 16g..16g+15); cols colbase = (tid&255)*4.
__global__ __launch_bounds__(512)
void rq_main(const float* __restrict__ z,
             const float* __restrict__ emb,
             const float* __restrict__ embT,
             const float* __restrict__ t2g,
             float* __restrict__ out) {
  __shared__ float At[256 * 36];     // res transposed [k][r], row stride 36 (= R4)
  __shared__ float Bb[2][4096];      // double-buffered 4k x 1024 chunk
  __shared__ float t2s[1024];
  __shared__ float t1part[32][16];
  __shared__ float t1s[32];
  __shared__ float redv[128];        // [32 rows][4 col-waves]
  __shared__ int redi[128];
  __shared__ int codes_l[128];       // [32 rows][4 depths]
  __shared__ float lossAcc;

  const int tid = threadIdx.x;
  const int w = tid >> 6, l = tid & 63;
  const int g = tid >> 8;            // row-group 0/1
  const int wg = (tid >> 6) & 3;     // col-wave within group (ascending cols)
  const int colbase = (tid & 255) << 2;
  const int n0 = blockIdx.x << 5;
  const int b = n0 >> 10, hw0 = n0 & 1023;
  const float* zbase = z + b * 262144 + hw0;

  // stage zf (transposed) into At (same as R4)
#pragma unroll
  for (int it = 0; it < 4; ++it) {
    int idx = it * 512 + tid;
    int k = idx >> 3, r4 = (idx & 7) << 2;
    *(float4*)(&At[k * 36 + r4]) = *(const float4*)(zbase + k * 1024 + r4);
  }
  {
    int i = tid << 1;
    float2 v = *(const float2*)(t2g + i);
    t2s[i] = v.x; t2s[i + 1] = v.y;
  }
  if (tid == 0) lossAcc = 0.0f;
  __syncthreads();

  const int rr_ = tid & 31, part_ = tid >> 5;
  const int kb0_ = (part_ >> 3) * 128 + (part_ & 7);

  for (int t = 0; t < 4; ++t) {
    // issue chunk-0 stage early; t1 phase's syncs hide its latency
    STAGE(0, 0)

    // ---- t1 = numpy pairwise sum of res^2 per row (bitwise, = R4) ----
    {
#pragma clang fp contract(off)
      float x = At[kb0_ * 36 + rr_];
      float acc = x * x;
      for (int i = 1; i < 16; ++i) {
        float y = At[(kb0_ + i * 8) * 36 + rr_];
        acc = acc + y * y;
      }
      t1part[rr_][part_] = acc;
    }
    __syncthreads();
    if (tid < 32) {
#pragma clang fp contract(off)
      const float* p = t1part[tid];
      float B0 = ((p[0] + p[1]) + (p[2] + p[3])) + ((p[4] + p[5]) + (p[6] + p[7]));
      float B1 = ((p[8] + p[9]) + (p[10] + p[11])) + ((p[12] + p[13]) + (p[14] + p[15]));
      t1s[tid] = B0 + B1;
    }
    __syncthreads();
    if (t > 0 && tid == 0) {
      float s = 0.0f;
      for (int r = 0; r < 32; ++r) s += t1s[r];
      lossAcc += s;
    }

    // ---- GEMM: 64 pipelined steps of 4k; 16 named float4 accumulators ----
    float4 c00 = {0.f,0.f,0.f,0.f}, c01 = c00, c02 = c00, c03 = c00;
    float4 c10 = c00, c11 = c00, c12 = c00, c13 = c00;
    float4 c20 = c00, c21 = c00, c22 = c00, c23 = c00;
    float4 c30 = c00, c31 = c00, c32 = c00, c33 = c00;
    for (int kc = 0; kc < 64; ++kc) {
      if (kc < 63) STAGE((kc + 1) & 1, kc + 1)   // prefetch next chunk
      const float* bb = &Bb[kc & 1][0];
#pragma unroll
      for (int k = 0; k < 4; ++k) {
        const float* arow = &At[((kc << 2) + k) * 36 + (g << 4)];
        float4 bv = *(const float4*)(bb + (k << 10) + colbase);
        float4 a0 = *(const float4*)(arow + 0);
        float4 a1 = *(const float4*)(arow + 4);
        float4 a2 = *(const float4*)(arow + 8);
        float4 a3 = *(const float4*)(arow + 12);
        FM(c00, a0, bv.x) FM(c01, a1, bv.x) FM(c02, a2, bv.x) FM(c03, a3, bv.x)
        FM(c10, a0, bv.y) FM(c11, a1, bv.y) FM(c12, a2, bv.y) FM(c13, a3, bv.y)
        FM(c20, a0, bv.z) FM(c21, a1, bv.z) FM(c22, a2, bv.z) FM(c23, a3, bv.z)
        FM(c30, a0, bv.w) FM(c31, a1, bv.w) FM(c32, a2, bv.w) FM(c33, a3, bv.w)
      }
      __syncthreads();   // drains this step's prefetch + separates buffer reuse
    }

    // ---- d = fl(fl(t1+t2) - 2*dot); argmin, first-index tie-break ----
    {
      float4 tc = *(const float4*)(&t2s[colbase]);
      const int g16 = g << 4;
      ARGMIN_ROW4(g16 + 0,  c00.x, c10.x, c20.x, c30.x)
      ARGMIN_ROW4(g16 + 1,  c00.y, c10.y, c20.y, c30.y)
      ARGMIN_ROW4(g16 + 2,  c00.z, c10.z, c20.z, c30.z)
      ARGMIN_ROW4(g16 + 3,  c00.w, c10.w, c20.w, c30.w)
      ARGMIN_ROW4(g16 + 4,  c01.x, c11.x, c21.x, c31.x)
      ARGMIN_ROW4(g16 + 5,  c01.y, c11.y, c21.y, c31.y)
      ARGMIN_ROW4(g16 + 6,  c01.z, c11.z, c21.z, c31.z)
      ARGMIN_ROW4(g16 + 7,  c01.w, c11.w, c21.w, c31.w)
      ARGMIN_ROW4(g16 + 8,  c02.x, c12.x, c22.x, c32.x)
      ARGMIN_ROW4(g16 + 9,  c02.y, c12.y, c22.y, c32.y)
      ARGMIN_ROW4(g16 + 10, c02.z, c12.z, c22.z, c32.z)
      ARGMIN_ROW4(g16 + 11, c02.w, c12.w, c22.w, c32.w)
      ARGMIN_ROW4(g16 + 12, c03.x, c13.x, c23.x, c33.x)
      ARGMIN_ROW4(g16 + 13, c03.y, c13.y, c23.y, c33.y)
      ARGMIN_ROW4(g16 + 14, c03.z, c13.z, c23.z, c33.z)
      ARGMIN_ROW4(g16 + 15, c03.w, c13.w, c23.w, c33.w)
    }
    __syncthreads();
    if (tid < 32) {
      int r = tid;
      float v = redv[r << 2];
      int ci = redi[r << 2];
#pragma unroll
      for (int w2 = 1; w2 < 4; ++w2) {    // ascending col ranges -> first-index kept
        float ov = redv[(r << 2) + w2];
        int oi = redi[(r << 2) + w2];
        bool better = (ov < v) || (ov == v && oi < ci);
        v = better ? ov : v;
        ci = better ? oi : ci;
      }
      codes_l[(r << 2) + t] = ci;
    }
    __syncthreads();

    // ---- res -= emb[code]  (elementwise f32, bitwise, = R4) ----
    {
      int c = codes_l[(rr_ << 2) + t];
      const float* er = emb + (c << 8) + (part_ << 4);
      int kb = part_ << 4;
      float4 e0 = *(const float4*)(er);
      float4 e1 = *(const float4*)(er + 4);
      float4 e2 = *(const float4*)(er + 8);
      float4 e3 = *(const float4*)(er + 12);
      At[(kb + 0) * 36 + rr_] -= e0.x;  At[(kb + 1) * 36 + rr_] -= e0.y;
      At[(kb + 2) * 36 + rr_] -= e0.z;  At[(kb + 3) * 36 + rr_] -= e0.w;
      At[(kb + 4) * 36 + rr_] -= e1.x;  At[(kb + 5) * 36 + rr_] -= e1.y;
      At[(kb + 6) * 36 + rr_] -= e1.z;  At[(kb + 7) * 36 + rr_] -= e1.w;
      At[(kb + 8) * 36 + rr_] -= e2.x;  At[(kb + 9) * 36 + rr_] -= e2.y;
      At[(kb + 10) * 36 + rr_] -= e2.z; At[(kb + 11) * 36 + rr_] -= e2.w;
      At[(kb + 12) * 36 + rr_] -= e3.x; At[(kb + 13) * 36 + rr_] -= e3.y;
      At[(kb + 14) * 36 + rr_] -= e3.z; At[(kb + 15) * 36 + rr_] -= e3.w;
    }
    __syncthreads();
  }  // depth loop

  // ---- final loss term: sumsq(res_4) ----
  {
#pragma clang fp contract(off)
    float x = At[kb0_ * 36 + rr_];
    float acc = x * x;
    for (int i = 1; i < 16; ++i) {
      float y = At[(kb0_ + i * 8) * 36 + rr_];
      acc = acc + y * y;
    }
    t1part[rr_][part_] = acc;
  }
  __syncthreads();
  if (tid < 32) {
#pragma clang fp contract(off)
    const float* p = t1part[tid];
    float B0 = ((p[0] + p[1]) + (p[2] + p[3])) + ((p[4] + p[5]) + (p[6] + p[7]));
    float B1 = ((p[8] + p[9]) + (p[10] + p[11])) + ((p[12] + p[13]) + (p[14] + p[15]));
    t1s[tid] = B0 + B1;
  }
  __syncthreads();
  if (tid == 0) {
    float s = 0.0f;
    for (int r = 0; r < 32; ++r) s += t1s[r];
    float total = lossAcc + s;
    atomicAdd(out + 8388608, total * (11.0f / 8388608.0f));
  }
  __syncthreads();

  // ---- z_q = agg chain (= R4). wave w -> rows 4w..4w+3, lane l -> dims 4l..4l+3 ----
  const int r0 = w << 2;
  float4 g0 = {0.f,0.f,0.f,0.f}, g1 = g0, g2 = g0, g3 = g0;
#pragma unroll
  for (int t = 0; t < 4; ++t) {
#define AGG_ROW(G, rr) {                                                  \
      int c = codes_l[((r0 + (rr)) << 2) + t];                            \
      float4 e4 = *(const float4*)(emb + (c << 8) + (l << 2));            \
      G.x += e4.x; G.y += e4.y; G.z += e4.z; G.w += e4.w; }
    AGG_ROW(g0, 0) AGG_ROW(g1, 1) AGG_ROW(g2, 2) AGG_ROW(g3, 3)
#undef AGG_ROW
  }
#define STORE_AGG(G, rr)                                                  \
  At[((l << 2) + 0) * 36 + r0 + (rr)] = G.x;                              \
  At[((l << 2) + 1) * 36 + r0 + (rr)] = G.y;                              \
  At[((l << 2) + 2) * 36 + r0 + (rr)] = G.z;                              \
  At[((l << 2) + 3) * 36 + r0 + (rr)] = G.w;
  STORE_AGG(g0, 0) STORE_AGG(g1, 1) STORE_AGG(g2, 2) STORE_AGG(g3, 3)
#undef STORE_AGG
  __syncthreads();
  float* zqbase = out + b * 262144 + hw0;
#pragma unroll
  for (int it = 0; it < 16; ++it) {
    int d = (it << 4) + (tid >> 5);
    int r = tid & 31;
    zqbase[d * 1024 + r] = At[d * 36 + r];
  }
  if (tid < 128) {
    int n = tid >> 2, tt = tid & 3;
    out[8388609 + ((n0 + n) << 2) + tt] = (float)codes_l[(n << 2) + tt];
  }
}

extern "C" void kernel_launch(void* const* d_in, const int* in_sizes, int n_in,
                              void* d_out, int out_size, void* d_ws, size_t ws_size,
                              hipStream_t stream) {
  const float* z = (const float*)d_in[0];
  const float* emb = (const float*)d_in[1];
  float* out = (float*)d_out;
  float* ws = (float*)d_ws;
  float* embT = ws;            // 262144 f32
  float* t2 = ws + 262144;     // 1024 f32

  hipLaunchKernelGGL(prep_transpose, dim3(64), dim3(256), 0, stream, emb, embT);
  hipLaunchKernelGGL(prep_t2, dim3(64), dim3(256), 0, stream, emb, t2, out);
  hipLaunchKernelGGL(rq_main, dim3(1024), dim3(512), 0, stream, z, emb, embT, t2, out);
}

// Round 11
// 1011.978 us; speedup vs baseline: 1.6614x; 1.1048x over previous
//
#include <hip/hip_runtime.h>

// z: [32, 256, 32, 32] f32 -> zf: [N=32768, D=256];  emb_w: [K=1024, D=256] f32
// out: z_q (8388608 f32, BCHW) | loss (1 f32) | codes (131072 f32, BHW x DEPTH)
// Bitwise-np distance pipeline (passing since R4, absmax 12.0):
//   t1 = np pairwise sum (128-block, 8-acc, fixed tree), dot = sequential-k FMA,
//   d = fl(fl(t1+t2) - 2*dot), argmin first-index tie-break, res -= emb[code].
// R11: B direct from L2 (global_load_dwordx4) -- only 2x intra-block reuse, not
//      worth LDS. Deletes Bb+t2s+all 256 GEMM barriers; LDS 77.8->41KB (2
//      blocks/CU with slack); GEMM is barrier-free load/FMA, unroll-4 pipelined.
//      R10 evidence: 1 block/CU resident (Occ 23%), VALUBusy 52%, barrier-
//      coupled lgkm stalls. Same B values, same k-ascending FMA chains ->
//      codes bitwise-unchanged.

// ---------------- prep: transpose emb -> embT [256][1024] (pure copy) ----------------
__global__ __launch_bounds__(256) void prep_transpose(const float* __restrict__ emb,
                                                      float* __restrict__ embT) {
  __shared__ float tile[64][65];
  int tb = blockIdx.x;
  int c0 = (tb & 15) << 6;
  int d0 = (tb >> 4) << 6;
  int tx = threadIdx.x & 63;
  int ty = threadIdx.x >> 6;
#pragma unroll
  for (int i = 0; i < 16; ++i) {
    int c = (i << 2) + ty;
    tile[c][tx] = emb[(c0 + c) * 256 + d0 + tx];
  }
  __syncthreads();
#pragma unroll
  for (int i = 0; i < 16; ++i) {
    int d = (i << 2) + ty;
    embT[(d0 + d) * 1024 + c0 + tx] = tile[tx][d];
  }
}

// ---------------- prep: t2[c] = ||e_c||^2 via numpy pairwise order; zero loss ----------------
__global__ __launch_bounds__(256) void prep_t2(const float* __restrict__ emb,
                                               float* __restrict__ t2,
                                               float* __restrict__ out) {
#pragma clang fp contract(off)
  __shared__ float partials[16][16];
  int ci = threadIdx.x >> 4, part = threadIdx.x & 15;
  int bb = part >> 3, jj = part & 7;
  int c = (blockIdx.x << 4) + ci;
  const float* e = emb + c * 256 + bb * 128 + jj;
  float x = e[0];
  float acc = x * x;
  for (int i = 1; i < 16; ++i) { float y = e[i * 8]; acc = acc + y * y; }
  partials[ci][part] = acc;
  __syncthreads();
  if (part == 0) {
    const float* p = partials[ci];
    float B0 = ((p[0] + p[1]) + (p[2] + p[3])) + ((p[4] + p[5]) + (p[6] + p[7]));
    float B1 = ((p[8] + p[9]) + (p[10] + p[11])) + ((p[12] + p[13]) + (p[14] + p[15]));
    t2[c] = B0 + B1;
    if (c == 0) out[8388608] = 0.0f;
  }
}

// componentwise FMA: C += A * s, per-element chains k-ascending (bitwise = R4)
#define FM(C, A, S)                                                       \
  C.x = __builtin_fmaf(A.x, (S), C.x); C.y = __builtin_fmaf(A.y, (S), C.y); \
  C.z = __builtin_fmaf(A.z, (S), C.z); C.w = __builtin_fmaf(A.w, (S), C.w);

// Per-row: 4 in-thread cols (ascending, strict <), 64-lane butterfly, stash.
#define ARGMIN_ROW4(r, A0, A1, A2, A3) {                                  \
    float t1r = t1s[r];                                                   \
    float d0 = (t1r + tc.x) - 2.0f * (A0);                                \
    float d1 = (t1r + tc.y) - 2.0f * (A1);                                \
    float d2 = (t1r + tc.z) - 2.0f * (A2);                                \
    float d3 = (t1r + tc.w) - 2.0f * (A3);                                \
    float v = d0; int ci = colbase;                                       \
    if (d1 < v) { v = d1; ci = colbase + 1; }                             \
    if (d2 < v) { v = d2; ci = colbase + 2; }                             \
    if (d3 < v) { v = d3; ci = colbase + 3; }                             \
    _Pragma("unroll")                                                     \
    for (int m = 1; m < 64; m <<= 1) {                                    \
      float ov = __shfl_xor(v, m, 64);                                    \
      int oi = __shfl_xor(ci, m, 64);                                     \
      bool better = (ov < v) || (ov == v && oi < ci);                     \
      v = better ? ov : v;                                                \
      ci = better ? oi : ci;                                              \
    }                                                                     \
    if (l == 0) { redv[((r) << 2) + wg] = v; redi[((r) << 2) + wg] = ci; } }

// ---------------- main fused kernel: 4 faithful f32 GEMM+argmin rounds ----------------
// 1024 blocks x 512 threads. Block: 32 rows x 1024 cols. Thread: 16 rows x 4 cols.
// Row-group g = tid>>8 (rows 16g..16g+15); cols colbase = (tid&255)*4.
// GEMM: A broadcast from LDS, B straight from L2 (embT is 1MB, L2-resident).
__global__ __launch_bounds__(512)
void rq_main(const float* __restrict__ z,
             const float* __restrict__ emb,
             const float* __restrict__ embT,
             const float* __restrict__ t2g,
             float* __restrict__ out) {
  __shared__ float At[256 * 36];     // res transposed [k][r], row stride 36 (= R4)
  __shared__ float t1part[32][16];
  __shared__ float t1s[32];
  __shared__ float redv[128];        // [32 rows][4 col-waves]
  __shared__ int redi[128];
  __shared__ int codes_l[128];       // [32 rows][4 depths]
  __shared__ float lossAcc;

  const int tid = threadIdx.x;
  const int w = tid >> 6, l = tid & 63;
  const int g = tid >> 8;            // row-group 0/1
  const int wg = (tid >> 6) & 3;     // col-wave within group (ascending cols)
  const int colbase = (tid & 255) << 2;
  const int n0 = blockIdx.x << 5;
  const int b = n0 >> 10, hw0 = n0 & 1023;
  const float* zbase = z + b * 262144 + hw0;

  // stage zf (transposed) into At (same as R4)
#pragma unroll
  for (int it = 0; it < 4; ++it) {
    int idx = it * 512 + tid;
    int k = idx >> 3, r4 = (idx & 7) << 2;
    *(float4*)(&At[k * 36 + r4]) = *(const float4*)(zbase + k * 1024 + r4);
  }
  if (tid == 0) lossAcc = 0.0f;
  __syncthreads();

  const int rr_ = tid & 31, part_ = tid >> 5;
  const int kb0_ = (part_ >> 3) * 128 + (part_ & 7);
  const float* bptr = embT + colbase;

  for (int t = 0; t < 4; ++t) {
    // ---- t1 = numpy pairwise sum of res^2 per row (bitwise, = R4) ----
    {
#pragma clang fp contract(off)
      float x = At[kb0_ * 36 + rr_];
      float acc = x * x;
      for (int i = 1; i < 16; ++i) {
        float y = At[(kb0_ + i * 8) * 36 + rr_];
        acc = acc + y * y;
      }
      t1part[rr_][part_] = acc;
    }
    __syncthreads();
    if (tid < 32) {
#pragma clang fp contract(off)
      const float* p = t1part[tid];
      float B0 = ((p[0] + p[1]) + (p[2] + p[3])) + ((p[4] + p[5]) + (p[6] + p[7]));
      float B1 = ((p[8] + p[9]) + (p[10] + p[11])) + ((p[12] + p[13]) + (p[14] + p[15]));
      t1s[tid] = B0 + B1;
    }
    __syncthreads();
    if (t > 0 && tid == 0) {
      float s = 0.0f;
      for (int r = 0; r < 32; ++r) s += t1s[r];
      lossAcc += s;
    }

    // ---- GEMM: barrier-free; B from L2, A broadcast from LDS ----
    float4 c00 = {0.f,0.f,0.f,0.f}, c01 = c00, c02 = c00, c03 = c00;
    float4 c10 = c00, c11 = c00, c12 = c00, c13 = c00;
    float4 c20 = c00, c21 = c00, c22 = c00, c23 = c00;
    float4 c30 = c00, c31 = c00, c32 = c00, c33 = c00;
#pragma unroll 4
    for (int k = 0; k < 256; ++k) {
      float4 bv = *(const float4*)(bptr + (k << 10));
      const float* arow = &At[k * 36 + (g << 4)];
      float4 a0 = *(const float4*)(arow + 0);
      float4 a1 = *(const float4*)(arow + 4);
      float4 a2 = *(const float4*)(arow + 8);
      float4 a3 = *(const float4*)(arow + 12);
      FM(c00, a0, bv.x) FM(c01, a1, bv.x) FM(c02, a2, bv.x) FM(c03, a3, bv.x)
      FM(c10, a0, bv.y) FM(c11, a1, bv.y) FM(c12, a2, bv.y) FM(c13, a3, bv.y)
      FM(c20, a0, bv.z) FM(c21, a1, bv.z) FM(c22, a2, bv.z) FM(c23, a3, bv.z)
      FM(c30, a0, bv.w) FM(c31, a1, bv.w) FM(c32, a2, bv.w) FM(c33, a3, bv.w)
    }

    // ---- d = fl(fl(t1+t2) - 2*dot); argmin, first-index tie-break ----
    {
      float4 tc = *(const float4*)(t2g + colbase);
      const int g16 = g << 4;
      ARGMIN_ROW4(g16 + 0,  c00.x, c10.x, c20.x, c30.x)
      ARGMIN_ROW4(g16 + 1,  c00.y, c10.y, c20.y, c30.y)
      ARGMIN_ROW4(g16 + 2,  c00.z, c10.z, c20.z, c30.z)
      ARGMIN_ROW4(g16 + 3,  c00.w, c10.w, c20.w, c30.w)
      ARGMIN_ROW4(g16 + 4,  c01.x, c11.x, c21.x, c31.x)
      ARGMIN_ROW4(g16 + 5,  c01.y, c11.y, c21.y, c31.y)
      ARGMIN_ROW4(g16 + 6,  c01.z, c11.z, c21.z, c31.z)
      ARGMIN_ROW4(g16 + 7,  c01.w, c11.w, c21.w, c31.w)
      ARGMIN_ROW4(g16 + 8,  c02.x, c12.x, c22.x, c32.x)
      ARGMIN_ROW4(g16 + 9,  c02.y, c12.y, c22.y, c32.y)
      ARGMIN_ROW4(g16 + 10, c02.z, c12.z, c22.z, c32.z)
      ARGMIN_ROW4(g16 + 11, c02.w, c12.w, c22.w, c32.w)
      ARGMIN_ROW4(g16 + 12, c03.x, c13.x, c23.x, c33.x)
      ARGMIN_ROW4(g16 + 13, c03.y, c13.y, c23.y, c33.y)
      ARGMIN_ROW4(g16 + 14, c03.z, c13.z, c23.z, c33.z)
      ARGMIN_ROW4(g16 + 15, c03.w, c13.w, c23.w, c33.w)
    }
    __syncthreads();
    if (tid < 32) {
      int r = tid;
      float v = redv[r << 2];
      int ci = redi[r << 2];
#pragma unroll
      for (int w2 = 1; w2 < 4; ++w2) {    // ascending col ranges -> first-index kept
        float ov = redv[(r << 2) + w2];
        int oi = redi[(r << 2) + w2];
        bool better = (ov < v) || (ov == v && oi < ci);
        v = better ? ov : v;
        ci = better ? oi : ci;
      }
      codes_l[(r << 2) + t] = ci;
    }
    __syncthreads();

    // ---- res -= emb[code]  (elementwise f32, bitwise, = R4) ----
    {
      int c = codes_l[(rr_ << 2) + t];
      const float* er = emb + (c << 8) + (part_ << 4);
      int kb = part_ << 4;
      float4 e0 = *(const float4*)(er);
      float4 e1 = *(const float4*)(er + 4);
      float4 e2 = *(const float4*)(er + 8);
      float4 e3 = *(const float4*)(er + 12);
      At[(kb + 0) * 36 + rr_] -= e0.x;  At[(kb + 1) * 36 + rr_] -= e0.y;
      At[(kb + 2) * 36 + rr_] -= e0.z;  At[(kb + 3) * 36 + rr_] -= e0.w;
      At[(kb + 4) * 36 + rr_] -= e1.x;  At[(kb + 5) * 36 + rr_] -= e1.y;
      At[(kb + 6) * 36 + rr_] -= e1.z;  At[(kb + 7) * 36 + rr_] -= e1.w;
      At[(kb + 8) * 36 + rr_] -= e2.x;  At[(kb + 9) * 36 + rr_] -= e2.y;
      At[(kb + 10) * 36 + rr_] -= e2.z; At[(kb + 11) * 36 + rr_] -= e2.w;
      At[(kb + 12) * 36 + rr_] -= e3.x; At[(kb + 13) * 36 + rr_] -= e3.y;
      At[(kb + 14) * 36 + rr_] -= e3.z; At[(kb + 15) * 36 + rr_] -= e3.w;
    }
    __syncthreads();
  }  // depth loop

  // ---- final loss term: sumsq(res_4) ----
  {
#pragma clang fp contract(off)
    float x = At[kb0_ * 36 + rr_];
    float acc = x * x;
    for (int i = 1; i < 16; ++i) {
      float y = At[(kb0_ + i * 8) * 36 + rr_];
      acc = acc + y * y;
    }
    t1part[rr_][part_] = acc;
  }
  __syncthreads();
  if (tid < 32) {
#pragma clang fp contract(off)
    const float* p = t1part[tid];
    float B0 = ((p[0] + p[1]) + (p[2] + p[3])) + ((p[4] + p[5]) + (p[6] + p[7]));
    float B1 = ((p[8] + p[9]) + (p[10] + p[11])) + ((p[12] + p[13]) + (p[14] + p[15]));
    t1s[tid] = B0 + B1;
  }
  __syncthreads();
  if (tid == 0) {
    float s = 0.0f;
    for (int r = 0; r < 32; ++r) s += t1s[r];
    float total = lossAcc + s;
    atomicAdd(out + 8388608, total * (11.0f / 8388608.0f));
  }
  __syncthreads();

  // ---- z_q = agg chain (= R4). wave w -> rows 4w..4w+3, lane l -> dims 4l..4l+3 ----
  const int r0 = w << 2;
  float4 g0 = {0.f,0.f,0.f,0.f}, g1 = g0, g2 = g0, g3 = g0;
#pragma unroll
  for (int t = 0; t < 4; ++t) {
#define AGG_ROW(G, rr) {                                                  \
      int c = codes_l[((r0 + (rr)) << 2) + t];                            \
      float4 e4 = *(const float4*)(emb + (c << 8) + (l << 2));            \
      G.x += e4.x; G.y += e4.y; G.z += e4.z; G.w += e4.w; }
    AGG_ROW(g0, 0) AGG_ROW(g1, 1) AGG_ROW(g2, 2) AGG_ROW(g3, 3)
#undef AGG_ROW
  }
#define STORE_AGG(G, rr)                                                  \
  At[((l << 2) + 0) * 36 + r0 + (rr)] = G.x;                              \
  At[((l << 2) + 1) * 36 + r0 + (rr)] = G.y;                              \
  At[((l << 2) + 2) * 36 + r0 + (rr)] = G.z;                              \
  At[((l << 2) + 3) * 36 + r0 + (rr)] = G.w;
  STORE_AGG(g0, 0) STORE_AGG(g1, 1) STORE_AGG(g2, 2) STORE_AGG(g3, 3)
#undef STORE_AGG
  __syncthreads();
  float* zqbase = out + b * 262144 + hw0;
#pragma unroll
  for (int it = 0; it < 16; ++it) {
    int d = (it << 4) + (tid >> 5);
    int r = tid & 31;
    zqbase[d * 1024 + r] = At[d * 36 + r];
  }
  if (tid < 128) {
    int n = tid >> 2, tt = tid & 3;
    out[8388609 + ((n0 + n) << 2) + tt] = (float)codes_l[(n << 2) + tt];
  }
}

extern "C" void kernel_launch(void* const* d_in, const int* in_sizes, int n_in,
                              void* d_out, int out_size, void* d_ws, size_t ws_size,
                              hipStream_t stream) {
  const float* z = (const float*)d_in[0];
  const float* emb = (const float*)d_in[1];
  float* out = (float*)d_out;
  float* ws = (float*)d_ws;
  float* embT = ws;            // 262144 f32
  float* t2 = ws + 262144;     // 1024 f32

  hipLaunchKernelGGL(prep_transpose, dim3(64), dim3(256), 0, stream, emb, embT);
  hipLaunchKernelGGL(prep_t2, dim3(64), dim3(256), 0, stream, emb, t2, out);
  hipLaunchKernelGGL(rq_main, dim3(1024), dim3(512), 0, stream, z, emb, embT, t2, out);
}